// Round 8
// baseline (213.938 us; speedup 1.0000x reference)
//
#include <hip/hip_runtime.h>

// ---------------------------------------------------------------------------
// 2-layer GCN + global mean pool, MI355X (gfx950).
//   A_hat = D^{-1/2}(A+I)D^{-1/2}
//   G' = dinv*(X @ W1) fp16 [MFMA fp16];  H'' = dinv*relu(dinv*A_sum(G')+b1)
//   out = pool(dinv*A_sum(H'')) @ W2 + b2
// R18 (from R14=196us best; R17 fdot2 = noise):
//   (1) FIXED per-bucket colidx regions (base = b*CAPQ static) -> bucket_deg
//       kernel + cross-bucket scan DELETED. Fill block is self-sufficient:
//       count degL -> dinv -> local scan -> sentinels -> fill. CSR row
//       extents in int2 rs2[{start,end}] (one 8B load/node in aggs).
//   (2) Fill fused back into the GEMM kernel (disjoint blocks). GEMM needs
//       dinv only at C-write: per-bucket ready-flag handshake (MFMA first,
//       then short spin; 880 blocks co-resident at launch_bounds(256,4) ->
//       no deadlock; agent-scope atomics for cross-XCD visibility).
//   (3) Pad-4 TRAFFIC, pad-8 SPACING: row starts stay 16B-aligned (space
//       scan uses pad8) but e1 = rs + pad4(deg) -> phantom gather edges
//       halved (~-11% agg traffic). Burst: 16/8/4 (4-burst = 8B colidx).
//   (4) Aggs: R14 accumulate (cvt+add), 32-bit row addressing.
// Launches: memset + 4 kernels (was memset + 6).
// ws_size is 256 MiB; we use ~33 MB.
// ---------------------------------------------------------------------------

#define D 128
#define NGRAPH 64
#define AGG_BLOCKS 2048   // 8192 waves = 32/CU
#define BUCK_SH 9         // bucket = dst >> 9 (width 512)
#define BUCK_W  512
#define MAXBUCK 128       // N <= 65536

typedef _Float16 h16x2 __attribute__((ext_vector_type(2)));
typedef _Float16 f16x8 __attribute__((ext_vector_type(8)));
typedef float    f32x4 __attribute__((ext_vector_type(4)));
typedef unsigned short u16x8 __attribute__((ext_vector_type(8)));
typedef unsigned short u16x4 __attribute__((ext_vector_type(4)));

__device__ __forceinline__ float2 h2f(unsigned u) {
    h16x2 h = __builtin_bit_cast(h16x2, u);
    return make_float2((float)h.x, (float)h.y);
}
__device__ __forceinline__ unsigned f2h(float x, float y) {
    h16x2 h;
    h.x = (_Float16)x;
    h.y = (_Float16)y;
    return __builtin_bit_cast(unsigned, h);
}

// --- diagnostic: all-zero output (ws too small) ----------------------------
__global__ void zero_out_kernel(float* __restrict__ out, int n) {
    int i = blockIdx.x * blockDim.x + threadIdx.x;
    if (i < n) out[i] = 0.f;
}

// --- K1: W1 pack (blocks 0..7) | zero sentinel rows (block 8) | bucket
//     scatter (blocks 9..): LDS histogram + per-block span reservation. -----
__global__ __launch_bounds__(256) void pack_scatter_kernel(const float* __restrict__ W1,
                                                           _Float16* __restrict__ WB,
                                                           const int* __restrict__ ei,
                                                           int* __restrict__ bcnt,
                                                           unsigned* __restrict__ buck,
                                                           unsigned* __restrict__ Gz,
                                                           unsigned* __restrict__ Hz,
                                                           int N, int E, int CAP) {
    int b = (int)blockIdx.x;
    int t = (int)threadIdx.x;
    if (b < 8) {
        // WB[((kt*8+nt)*64+lane)*8+j] = W1[(kt*32+(lane>>4)*8+j)*D + nt*16+(lane&15)]
        int idx = b * 256 + t;                         // 0..2047
        int lane = idx & 63;
        int nt   = (idx >> 6) & 7;
        int kt   = idx >> 9;
        int col  = nt * 16 + (lane & 15);
        int krow = kt * 32 + (lane >> 4) * 8;
#pragma unroll
        for (int j = 0; j < 8; ++j)
            WB[idx * 8 + j] = (_Float16)W1[(krow + j) * D + col];
        return;
    }
    if (b == 8) {
        if (t < 64)       Gz[(size_t)N * 64 + t] = 0u;          // Gh row N = 0
        else if (t < 128) Hz[(size_t)N * 64 + (t - 64)] = 0u;   // Hh row N = 0
        return;
    }
    __shared__ unsigned histL[MAXBUCK];
    __shared__ int      baseL[MAXBUCK];
    if (t < MAXBUCK) histL[t] = 0u;
    __syncthreads();

    int e0 = (b - 9) * 1024;
    int bid[4];
    unsigned lidx[4], pk[4];
#pragma unroll
    for (int j = 0; j < 4; ++j) {
        int e = e0 + t + j * 256;
        bid[j] = -1;
        if (e < E) {
            int s = ei[e];
            int d = ei[E + e];
            if (d >= 0 && d < N) {
                s = min(max(s, 0), N - 1);
                bid[j] = d >> BUCK_SH;
                pk[j]  = ((unsigned)d << 16) | (unsigned)s;
            }
        }
    }
#pragma unroll
    for (int j = 0; j < 4; ++j)
        if (bid[j] >= 0) lidx[j] = atomicAdd(&histL[bid[j]], 1u);
    __syncthreads();
    if (t < MAXBUCK && histL[t] > 0u)
        baseL[t] = atomicAdd(&bcnt[t], (int)histL[t]);
    __syncthreads();
#pragma unroll
    for (int j = 0; j < 4; ++j)
        if (bid[j] >= 0) {
            int slot = baseL[bid[j]] + (int)lidx[j];
            if (slot < CAP) buck[(size_t)bid[j] * CAP + slot] = pk[j];
        }
}

// --- K2: blocks [0,nbuck): per-bucket CSR build (count -> dinv -> scan ->
//     sentinels -> fill) at FIXED base b*CAPQ; sets flags[b] after dinv.
//     Blocks [nbuck,nbuck+gb): MFMA GEMM; spin on flags[bucket] before the
//     dinv-scaled C-write. Zero global per-edge atomics.
__global__ __launch_bounds__(256, 4) void gemm_fill_kernel(const float* __restrict__ X,
                                                           const _Float16* __restrict__ WB,
                                                           const unsigned* __restrict__ buck,
                                                           const int* __restrict__ bcnt,
                                                           float* __restrict__ dinv,
                                                           int2* __restrict__ rs2,
                                                           unsigned short* __restrict__ colidx,
                                                           int* __restrict__ flags,
                                                           _Float16* __restrict__ Gh,
                                                           int N, int CAP, int CAPQ, int nbuck) {
    int t = (int)threadIdx.x;
    if ((int)blockIdx.x < nbuck) {
        __shared__ int degS[BUCK_W];    // deg, later absolute cursors
        __shared__ int loff[BUCK_W];
        __shared__ int sc[256];
        int b = (int)blockIdx.x;
        for (int k = t; k < BUCK_W; k += 256) degS[k] = 0;
        __syncthreads();
        int cnt = min(bcnt[b], CAP);
        const unsigned* bp = buck + (size_t)b * CAP;
        for (int i = t; i < cnt; i += 256)
            atomicAdd(&degS[(bp[i] >> 16) & (BUCK_W - 1)], 1);
        __syncthreads();
        // scan of pad8 SPACE (keeps row starts 16B-aligned); traffic is pad4
        int d0 = degS[2 * t], d1 = degS[2 * t + 1];
        int p0 = (d0 + 7) & ~7;
        int p1 = (d1 + 7) & ~7;
        int own = p0 + p1;
        sc[t] = own;
        __syncthreads();
        for (int off = 1; off < 256; off <<= 1) {
            int v = (t >= off) ? sc[t - off] : 0;
            __syncthreads();
            sc[t] += v;
            __syncthreads();
        }
        int excl = sc[t] - own;
        loff[2 * t]     = excl;
        loff[2 * t + 1] = excl + p0;
        __syncthreads();
        int BB = b * CAPQ;
        int base_d = b << BUCK_SH;
        // dinv (agent-scope stores) + rs2 + sentinel pads [deg, pad4)
        for (int k = t; k < BUCK_W; k += 256) {
            int d = base_d + k;
            if (d < N) {
                int dg = degS[k];
                int rs = BB + loff[k];
                int p4 = (dg + 3) & ~3;
                __hip_atomic_store(&dinv[d], rsqrtf((float)dg + 1.0f),
                                   __ATOMIC_RELAXED, __HIP_MEMORY_SCOPE_AGENT);
                rs2[d] = make_int2(rs, rs + p4);
                for (int j = dg; j < p4; ++j)
                    colidx[rs + j] = (unsigned short)N;   // sentinel -> zero row
            }
        }
        __syncthreads();
        if (t == 0) {                         // release dinv for GEMM blocks
            __threadfence();
            atomicExch(&flags[b], 1);
        }
        // convert degS -> absolute cursors
        for (int k = t; k < BUCK_W; k += 256) degS[k] = BB + loff[k];
        __syncthreads();
        for (int i = t; i < cnt; i += 256) {
            unsigned u = bp[i];
            int ld = (int)((u >> 16) & (BUCK_W - 1));
            int slot = atomicAdd(&degS[ld], 1);           // LDS atomic
            colidx[slot] = (unsigned short)(u & 0xffffu);
        }
        return;
    }

    int gbid = (int)blockIdx.x - nbuck;
    int wave = t >> 6, lane = t & 63;
    int mbase = gbid * 64 + wave * 16;
    int arow  = mbase + (lane & 15);
    if (arow >= N) arow = N - 1;             // clamped duplicate reads
    int kgrp  = lane >> 4;                   // 0..3

    // A-frag: lane holds X[arow][kt*32 + kgrp*8 .. +8], converted to fp16
    f16x8 afrag[4];
#pragma unroll
    for (int kt = 0; kt < 4; ++kt) {
        const float* xp = X + (size_t)arow * D + kt * 32 + kgrp * 8;
        float4 a0 = *(const float4*)xp;
        float4 a1 = *(const float4*)(xp + 4);
        f16x8 af;
        af[0] = (_Float16)a0.x; af[1] = (_Float16)a0.y;
        af[2] = (_Float16)a0.z; af[3] = (_Float16)a0.w;
        af[4] = (_Float16)a1.x; af[5] = (_Float16)a1.y;
        af[6] = (_Float16)a1.z; af[7] = (_Float16)a1.w;
        afrag[kt] = af;
    }
    f32x4 acc[8];
#pragma unroll
    for (int nt = 0; nt < 8; ++nt) acc[nt] = (f32x4){0.f, 0.f, 0.f, 0.f};
#pragma unroll
    for (int kt = 0; kt < 4; ++kt) {
#pragma unroll
        for (int nt = 0; nt < 8; ++nt) {
            uint4 u = *(const uint4*)(WB + (((kt * 8 + nt) * 64 + lane) * 8));
            f16x8 bfrag = __builtin_bit_cast(f16x8, u);
            acc[nt] = __builtin_amdgcn_mfma_f32_16x16x32_f16(afrag[kt], bfrag, acc[nt], 0, 0, 0);
        }
    }
    // wait for dinv of this block's bucket (64 rows within one 512-bucket)
    int mybuck = gbid >> 3;                  // (gbid*64) >> BUCK_SH
    if (mybuck >= nbuck) mybuck = nbuck - 1;
    if (t == 0) {
        while (atomicAdd(&flags[mybuck], 0) == 0) __builtin_amdgcn_s_sleep(16);
        __threadfence();
    }
    __syncthreads();
    // C/D: col = lane&15, row = kgrp*4 + reg   [m89-verified, dtype-indep]
    int r0 = mbase + kgrp * 4;
#pragma unroll
    for (int r = 0; r < 4; ++r) {
        int row = r0 + r;
        if (row < N) {
            float dv = __hip_atomic_load(&dinv[row], __ATOMIC_RELAXED,
                                         __HIP_MEMORY_SCOPE_AGENT);
#pragma unroll
            for (int nt = 0; nt < 8; ++nt)
                Gh[(size_t)row * D + nt * 16 + (lane & 15)] = (_Float16)(dv * acc[nt][r]);
        }
    }
}

// --- agg1: H''_i = dinv_i * relu(dinv_i*(sum_e G'_s + G'_i) + b1), fp16 -----
// 64-lane wave per node; pad-4 CSR -> branchless 16/8/4 gather bursts.
__global__ __launch_bounds__(256) void agg1_kernel(const unsigned* __restrict__ Gh,
                                                   const int2* __restrict__ rs2,
                                                   const unsigned short* __restrict__ colidx,
                                                   const float* __restrict__ dinv,
                                                   const float* __restrict__ b1,
                                                   unsigned* __restrict__ Hh,
                                                   int N, int chunk) {
    int gid  = blockIdx.x * 4 + (threadIdx.x >> 6);
    unsigned lane = threadIdx.x & 63;
    int i0 = gid * chunk, i1 = min(i0 + chunk, N);
    float bx = b1[2 * lane], by = b1[2 * lane + 1];
    for (int i = i0; i < i1; ++i) {
        float di = dinv[i];
        float2 s = h2f(Gh[((unsigned)i << 6) + lane]);      // self term
        float ax = s.x, ay = s.y;
        int2 se = rs2[i];
        int e = se.x, e1 = se.y;                            // e 8-aligned, len mult of 4
        for (; e + 15 < e1; e += 16) {
            u16x8 c0 = *(const u16x8*)(colidx + e);         // 16B, aligned
            u16x8 c1 = *(const u16x8*)(colidx + e + 8);
            unsigned u[16];
#pragma unroll
            for (int j = 0; j < 8; ++j)
                u[j] = Gh[((unsigned)c0[j] << 6) + lane];
#pragma unroll
            for (int j = 0; j < 8; ++j)
                u[8 + j] = Gh[((unsigned)c1[j] << 6) + lane];
#pragma unroll
            for (int j = 0; j < 16; ++j) {
                float2 v = h2f(u[j]);
                ax += v.x;
                ay += v.y;
            }
        }
        if (e + 7 < e1) {
            u16x8 cc = *(const u16x8*)(colidx + e);
            unsigned u[8];
#pragma unroll
            for (int j = 0; j < 8; ++j)
                u[j] = Gh[((unsigned)cc[j] << 6) + lane];
#pragma unroll
            for (int j = 0; j < 8; ++j) {
                float2 v = h2f(u[j]);
                ax += v.x;
                ay += v.y;
            }
            e += 8;
        }
        if (e + 3 < e1) {
            u16x4 cc = *(const u16x4*)(colidx + e);         // 8B, aligned
            unsigned u[4];
#pragma unroll
            for (int j = 0; j < 4; ++j)
                u[j] = Gh[((unsigned)cc[j] << 6) + lane];
#pragma unroll
            for (int j = 0; j < 4; ++j) {
                float2 v = h2f(u[j]);
                ax += v.x;
                ay += v.y;
            }
        }
        float hx = fmaxf(fmaf(di, ax, bx), 0.f) * di;       // H'' = dinv*relu
        float hy = fmaxf(fmaf(di, ay, by), 0.f) * di;
        Hh[((unsigned)i << 6) + lane] = f2h(hx, hy);
    }
}

// --- agg2 + pool: pool[batch_i] += dinv_i*(sum_e H''_s + H''_i) -------------
__global__ __launch_bounds__(256) void agg2_pool_kernel(const unsigned* __restrict__ Hh,
                                                        const int2* __restrict__ rs2,
                                                        const unsigned short* __restrict__ colidx,
                                                        const float* __restrict__ dinv,
                                                        const int* __restrict__ batch,
                                                        float* __restrict__ pool,
                                                        int N, int chunk) {
    int gid  = blockIdx.x * 4 + (threadIdx.x >> 6);
    unsigned lane = threadIdx.x & 63;
    int i0 = gid * chunk, i1 = min(i0 + chunk, N);
    if (i0 >= N) return;

    float2 pa = make_float2(0.f, 0.f);
    int cur = min(max(batch[i0], 0), NGRAPH - 1);
    for (int i = i0; i < i1; ++i) {
        float di = dinv[i];
        float2 s = h2f(Hh[((unsigned)i << 6) + lane]);      // self term
        float ax = s.x, ay = s.y;
        int2 se = rs2[i];
        int e = se.x, e1 = se.y;
        for (; e + 15 < e1; e += 16) {
            u16x8 c0 = *(const u16x8*)(colidx + e);
            u16x8 c1 = *(const u16x8*)(colidx + e + 8);
            unsigned u[16];
#pragma unroll
            for (int j = 0; j < 8; ++j)
                u[j] = Hh[((unsigned)c0[j] << 6) + lane];
#pragma unroll
            for (int j = 0; j < 8; ++j)
                u[8 + j] = Hh[((unsigned)c1[j] << 6) + lane];
#pragma unroll
            for (int j = 0; j < 16; ++j) {
                float2 v = h2f(u[j]);
                ax += v.x;
                ay += v.y;
            }
        }
        if (e + 7 < e1) {
            u16x8 cc = *(const u16x8*)(colidx + e);
            unsigned u[8];
#pragma unroll
            for (int j = 0; j < 8; ++j)
                u[j] = Hh[((unsigned)cc[j] << 6) + lane];
#pragma unroll
            for (int j = 0; j < 8; ++j) {
                float2 v = h2f(u[j]);
                ax += v.x;
                ay += v.y;
            }
            e += 8;
        }
        if (e + 3 < e1) {
            u16x4 cc = *(const u16x4*)(colidx + e);
            unsigned u[4];
#pragma unroll
            for (int j = 0; j < 4; ++j)
                u[j] = Hh[((unsigned)cc[j] << 6) + lane];
#pragma unroll
            for (int j = 0; j < 4; ++j) {
                float2 v = h2f(u[j]);
                ax += v.x;
                ay += v.y;
            }
        }
        int b = min(max(batch[i], 0), NGRAPH - 1);
        if (b != cur) {                                     // uniform per wave
            atomicAdd(&pool[(size_t)cur * D + 2 * lane], pa.x);
            atomicAdd(&pool[(size_t)cur * D + 2 * lane + 1], pa.y);
            pa = make_float2(0.f, 0.f);
            cur = b;
        }
        pa.x = fmaf(di, ax, pa.x);
        pa.y = fmaf(di, ay, pa.y);
    }
    atomicAdd(&pool[(size_t)cur * D + 2 * lane], pa.x);
    atomicAdd(&pool[(size_t)cur * D + 2 * lane + 1], pa.y);
}

// --- Final tiny GEMM: out[g][o] = (pool[g]/cnt_g) . W2[:,o] + b2[o] ---------
__device__ __forceinline__ int lbound(const int* __restrict__ a, int n, int v) {
    int lo = 0, hi = n;
    while (lo < hi) {
        int m = (lo + hi) >> 1;
        if (a[m] < v) lo = m + 1; else hi = m;
    }
    return lo;
}

__global__ void final_gemm_kernel(const float* __restrict__ pool,
                                  const int* __restrict__ batch,
                                  const float* __restrict__ W2,
                                  const float* __restrict__ b2,
                                  float* __restrict__ out, int N) {
    int g = blockIdx.x, o = threadIdx.x;
    int s = lbound(batch, N, g);
    int e = lbound(batch, N, g + 1);
    float inv_cnt = 1.0f / fmaxf((float)(e - s), 1.0f);
    float acc = 0.f;
#pragma unroll 4
    for (int k = 0; k < D; ++k)
        acc = fmaf(pool[g * D + k], W2[k * D + o], acc);
    out[g * D + o] = acc * inv_cnt + b2[o];
}

// ---------------------------------------------------------------------------

extern "C" void kernel_launch(void* const* d_in, const int* in_sizes, int n_in,
                              void* d_out, int out_size, void* d_ws, size_t ws_size,
                              hipStream_t stream) {
    const float* x     = (const float*)d_in[0];
    const int*   ei    = (const int*)  d_in[1];
    const int*   batch = (const int*)  d_in[2];
    const float* W1    = (const float*)d_in[3];
    const float* b1    = (const float*)d_in[4];
    const float* W2    = (const float*)d_in[5];
    const float* b2    = (const float*)d_in[6];
    float* out = (float*)d_out;

    const int N = in_sizes[0] / D;
    const int E = in_sizes[1] / 2;
    const int nbuck = (N + BUCK_W - 1) >> BUCK_SH;      // <=128 for N<=65536
    const int CAP   = (E / (nbuck > 0 ? nbuck : 1)) * 2 + 1024;
    const int CAPQ  = CAP + 8 * BUCK_W;                 // + worst-case pad8 space

    // workspace carve-up (256B aligned); bcnt+pool+flags -> single memset
    char* ws = (char*)d_ws;
    size_t off = 0;
    auto carve = [&](size_t bytes) {
        size_t o = off;
        off = (off + bytes + 255) & ~(size_t)255;
        return o;
    };
    size_t o_bcnt     = carve((size_t)MAXBUCK * 4);
    size_t o_pool     = carve((size_t)NGRAPH * D * 4);
    size_t o_flags    = carve((size_t)MAXBUCK * 4);
    size_t zspan      = off;                       // memset [0, zspan)
    size_t o_rs2      = carve((size_t)N * 8);
    size_t o_dinv     = carve((size_t)N * 4);
    size_t o_colidx   = carve((size_t)nbuck * CAPQ * 2);
    size_t o_buck     = carve((size_t)nbuck * CAP * 4);
    size_t o_wb       = carve((size_t)D * D * 2);        // fp16 W1 (MFMA B)
    size_t o_gh       = carve((size_t)(N + 1) * D * 2);  // fp16 G' (+zero row)
    size_t o_hh       = carve((size_t)(N + 1) * D * 2);  // fp16 H'' (+zero row)
    size_t need = off;

    if (ws_size < need) {
        zero_out_kernel<<<(out_size + 255) / 256, 256, 0, stream>>>(out, out_size);
        return;
    }

    int*            bcnt     = (int*)           (ws + o_bcnt);
    float*          pool     = (float*)         (ws + o_pool);
    int*            flags    = (int*)           (ws + o_flags);
    int2*           rs2      = (int2*)          (ws + o_rs2);
    float*          dinv     = (float*)         (ws + o_dinv);
    unsigned short* colidx   = (unsigned short*)(ws + o_colidx);
    unsigned*       buck     = (unsigned*)      (ws + o_buck);
    _Float16*       WB       = (_Float16*)      (ws + o_wb);
    _Float16*       Gh       = (_Float16*)      (ws + o_gh);
    _Float16*       Hh       = (_Float16*)      (ws + o_hh);

    hipMemsetAsync(ws, 0, zspan, stream);          // bcnt + pool + flags

    int ebs = (E + 1023) / 1024;                   // scatter: 4 edges/thread
    int gb  = (N + 63) / 64;

    pack_scatter_kernel<<<9 + ebs, 256, 0, stream>>>(W1, WB, ei, bcnt, buck,
                                                     (unsigned*)Gh, (unsigned*)Hh,
                                                     N, E, CAP);
    gemm_fill_kernel<<<nbuck + gb, 256, 0, stream>>>(x, WB, buck, bcnt, dinv, rs2,
                                                     colidx, flags, Gh,
                                                     N, CAP, CAPQ, nbuck);

    int groups = AGG_BLOCKS * 4;
    int chunk  = (N + groups - 1) / groups;
    agg1_kernel<<<AGG_BLOCKS, 256, 0, stream>>>((const unsigned*)Gh, rs2, colidx,
                                                dinv, b1, (unsigned*)Hh, N, chunk);
    agg2_pool_kernel<<<AGG_BLOCKS, 256, 0, stream>>>((const unsigned*)Hh, rs2, colidx,
                                                     dinv, batch, pool, N, chunk);
    final_gemm_kernel<<<NGRAPH, D, 0, stream>>>(pool, batch, W2, b2, out, N);
}